// Round 6
// baseline (119.720 us; speedup 1.0000x reference)
//
#include <hip/hip_runtime.h>
#include <hip/hip_bf16.h>
#include <math.h>

#define NSLICES 1024
#define DIM     768
#define NPTS    256
#define K_REF   17
#define KSPLIT  4
#define KCHUNK  (DIM / KSPLIT)      // 192
#define XSZ     (NSLICES * NPTS)    // 262144 floats per (z, kchunk) partial

// ws float layout — every slot is rewritten every call (no zero-init needed)
#define INV_OFF 0                   // 64 partials
#define G_OFF   208                 // 17 scaled reference points
#define TICKET_OFF 240              // int ticket for last-block detection (reset by kernel1)
#define SIG_OFF 256                 // 2048 partials
#define XP_OFF  2560                // projection partials

#define EXP2(x) __builtin_amdgcn_exp2f(x)
// y = x * SCALE_A  =>  exp(-0.5(xi-xj)^2) == exp2(-(yi-yj)^2)
#define SCALE_A 0.84932180028801904272f      // sqrt(0.5 * log2(e))
#define INV_N2  1.52587890625e-05f           // 1/256^2
#define T2_SC   4.595588235294118e-4f        // 2/(256*17)

__device__ __forceinline__ float wave_sum(float v) {
#pragma unroll
    for (int o = 32; o; o >>= 1) v += __shfl_xor(v, o, 64);
    return v;
}

__device__ __forceinline__ float block_sum_256(float v, float* wred, int tid) {
    v = wave_sum(v);
    if ((tid & 63) == 0) wred[tid >> 6] = v;
    __syncthreads();
    float r = wred[0] + wred[1] + wred[2] + wred[3];
    __syncthreads();
    return r;
}

// ---------------- kernel 1: proj GEMM + fused inv partials ------------------
// grid (4, 16, 2*KSPLIT + 1), block 256.
//  z < 8 : proj blocks — 64x64 tile, 4x4/thread, K-chunk of 192 (round-4 shape).
//  z == 8: 64 inv blocks (idx = mt*4+nt) + block 0 writes g + resets ticket.
__global__ __launch_bounds__(256) void proj_inv_kernel(const float* __restrict__ za,
                                                       const float* __restrict__ zb,
                                                       const float* __restrict__ slices,
                                                       float* __restrict__ w, int npart) {
    const int tid = threadIdx.x;

    if (blockIdx.z == 2 * KSPLIT) {
        // ---- inv path: 64 blocks, 49152 float4s total, 3 per thread ----
        __shared__ float wred[4];
        const int b = blockIdx.y * 4 + blockIdx.x;      // 0..63
        const float4* A = (const float4*)za;
        const float4* B = (const float4*)zb;
        float p = 0.f;
#pragma unroll
        for (int i = 0; i < 3; ++i) {
            int idx = b * 768 + i * 256 + tid;
            float4 a = A[idx], bb = B[idx];
            float dx = a.x - bb.x, dy = a.y - bb.y, dz = a.z - bb.z, dw = a.w - bb.w;
            p += dx * dx + dy * dy + dz * dz + dw * dw;
        }
        float s = block_sum_256(p, wred, tid);
        if (tid == 0) w[INV_OFF + b] = s;
        if (b == 0) {
            if (tid < K_REF) {
                float q = 0.01f + 0.06125f * (float)tid;
                w[G_OFF + tid] = erfinvf(2.0f * q - 1.0f) * 1.41421356237309504880f * SCALE_A;
            }
            if (tid == 32) *(int*)&w[TICKET_OFF] = 0;   // reset last-block ticket
        }
        return;
    }

    // ---- proj path (round-4 measured-good shape, K-chunk 192) ----
    __shared__ float sA[16][68];
    __shared__ float sB[16][68];
    const int nt = blockIdx.x;            // 0..3
    const int mt = blockIdx.y;            // 0..15
    const int zi = blockIdx.z >> 2;       // 0..1
    const int kc = blockIdx.z & 3;        // 0..3
    const float* Z = zi ? zb : za;
    const int m0 = mt * 64, n0 = nt * 64;
    const int tx = tid & 15, ty = tid >> 4;
    const int lr = tid >> 2, lq = tid & 3;      // loader: row 0..63, quad 0..3
    const int kbase = kc * KCHUNK;

    float acc[4][4] = {};

    for (int k0 = 0; k0 < KCHUNK; k0 += 16) {
        float4 av = *(const float4*)(slices + (size_t)(m0 + lr) * DIM + kbase + k0 + lq * 4);
        float4 bv = *(const float4*)(Z + (size_t)(n0 + lr) * DIM + kbase + k0 + lq * 4);
        // transposed store: sA[kk][m]
        sA[lq * 4 + 0][lr] = av.x; sA[lq * 4 + 1][lr] = av.y;
        sA[lq * 4 + 2][lr] = av.z; sA[lq * 4 + 3][lr] = av.w;
        sB[lq * 4 + 0][lr] = bv.x; sB[lq * 4 + 1][lr] = bv.y;
        sB[lq * 4 + 2][lr] = bv.z; sB[lq * 4 + 3][lr] = bv.w;
        __syncthreads();
#pragma unroll
        for (int kk = 0; kk < 16; ++kk) {
            float4 a = *(const float4*)&sA[kk][ty * 4];
            float4 b = *(const float4*)&sB[kk][tx * 4];
            acc[0][0] += a.x * b.x; acc[0][1] += a.x * b.y; acc[0][2] += a.x * b.z; acc[0][3] += a.x * b.w;
            acc[1][0] += a.y * b.x; acc[1][1] += a.y * b.y; acc[1][2] += a.y * b.z; acc[1][3] += a.y * b.w;
            acc[2][0] += a.z * b.x; acc[2][1] += a.z * b.y; acc[2][2] += a.z * b.z; acc[2][3] += a.z * b.w;
            acc[3][0] += a.w * b.x; acc[3][1] += a.w * b.y; acc[3][2] += a.w * b.z; acc[3][3] += a.w * b.w;
        }
        __syncthreads();
    }

    if (npart == KSPLIT) {
        float* X = w + XP_OFF + ((size_t)zi * KSPLIT + kc) * XSZ;
#pragma unroll
        for (int i = 0; i < 4; ++i) {
            float4 o; o.x = acc[i][0]; o.y = acc[i][1]; o.z = acc[i][2]; o.w = acc[i][3];
            *(float4*)(X + (size_t)(m0 + ty * 4 + i) * NPTS + n0 + tx * 4) = o;
        }
    } else {
        float* X = w + XP_OFF + (size_t)zi * XSZ;
#pragma unroll
        for (int i = 0; i < 4; ++i)
#pragma unroll
            for (int j = 0; j < 4; ++j)
                atomicAdd(X + (size_t)(m0 + ty * 4 + i) * NPTS + n0 + tx * 4 + j, acc[i][j]);
    }
}

// ---------------- kernel 2: sigreg (t1 + t2) + last-block final combine -----
// grid: (NSLICES, 2); block 256 (one thread per sample point).
// t1 off-diagonal: circular offsets o=1..128; total = 2*s1 - s128 (+ diagonal N).
__global__ __launch_bounds__(256) void sigreg_kernel(float* __restrict__ w,
                                                     float* __restrict__ out, int npart) {
    __shared__ float ys[2 * NPTS];     // duplicated so reads are base + imm offset
    __shared__ float gsh[K_REF];
    __shared__ float wred[4];
    __shared__ int is_last;
    const int m = blockIdx.x;
    const int zi = blockIdx.y;
    const int tid = threadIdx.x;

    const float* Xb = w + XP_OFF + (size_t)zi * npart * XSZ + (size_t)m * NPTS + tid;
    float xv = 0.f;
    for (int p = 0; p < npart; ++p) xv += Xb[(size_t)p * XSZ];
    if (tid < K_REF) gsh[tid] = w[G_OFF + tid];

    float mu = block_sum_256(xv, wred, tid) * (1.0f / NPTS);
    float dv = xv - mu;
    float ss = block_sum_256(dv * dv, wred, tid);
    float sd = sqrtf(ss * (1.0f / (NPTS - 1))) + 1e-6f;
    float yv = (dv / sd) * SCALE_A;
    ys[tid] = yv;
    ys[tid + NPTS] = yv;
    __syncthreads();

    float s1a = 0.f, s1b = 0.f;
#pragma unroll 8
    for (int o = 1; o <= 128; o += 2) {
        float d0 = yv - ys[tid + o];
        float d1 = yv - ys[tid + o + 1];
        s1a += EXP2(-(d0 * d0));
        s1b += EXP2(-(d1 * d1));
    }
    float d128 = yv - ys[tid + 128];
    float s128 = EXP2(-(d128 * d128));
    float s2 = 0.f;
#pragma unroll
    for (int k = 0; k < K_REF; ++k) {
        float d = yv - gsh[k];
        s2 += EXP2(-(d * d));
    }
    // off-diag = 2*(s1 incl o=128) - s128 ; diagonal N added at tid 0
    float c = (2.0f * (s1a + s1b) - s128) * INV_N2 - s2 * T2_SC;
    if (tid == 0) c += (float)NPTS * INV_N2;
    float tot = block_sum_256(c, wred, tid);
    if (tid == 0) {
        w[SIG_OFF + zi * NSLICES + m] = tot * (0.5f / (float)NSLICES);
        __threadfence();                              // release partial
        int old = atomicAdd((int*)&w[TICKET_OFF], 1);
        is_last = (old == 2 * NSLICES - 1);
    }
    __syncthreads();
    if (!is_last) return;

    // ---- last block: final combine ----
    __threadfence();                                  // acquire all partials
    float sv = 0.f;
#pragma unroll
    for (int i = tid; i < 2 * NSLICES; i += 256) sv += w[SIG_OFF + i];
    float iv = (tid < 64) ? w[INV_OFF + tid] : 0.f;
    float sig = block_sum_256(sv, wred, tid);
    float inv = block_sum_256(iv, wred, tid);
    float t3p = 0.f;
    for (int idx = tid; idx < K_REF * K_REF; idx += 256) {
        int k = idx / K_REF, l = idx - k * K_REF;
        float d = gsh[k] - gsh[l];
        t3p += EXP2(-(d * d));
    }
    float t3 = block_sum_256(t3p, wred, tid) * (1.0f / ((float)K_REF * (float)K_REF));
    if (tid == 0) {
        out[0] = 25.0f * inv * (1.0f / ((float)NPTS * (float)DIM))
               + 25.0f * (sig + t3);
    }
}

extern "C" void kernel_launch(void* const* d_in, const int* in_sizes, int n_in,
                              void* d_out, int out_size, void* d_ws, size_t ws_size,
                              hipStream_t stream) {
    const float* za = (const float*)d_in[0];
    const float* zb = (const float*)d_in[1];
    const float* slices = (const float*)d_in[2];
    float* out = (float*)d_out;
    float* w = (float*)d_ws;

    const size_t need_full = (size_t)(XP_OFF + 2 * KSPLIT * XSZ) * sizeof(float); // ~8.4 MB
    const int npart = (ws_size >= need_full) ? KSPLIT : 1;

    if (npart == 1)   // fallback only (harness ws is plenty; never taken)
        hipMemsetAsync(w + XP_OFF, 0, (size_t)2 * XSZ * sizeof(float), stream);

    dim3 pg(4, 16, 2 * KSPLIT + 1);
    proj_inv_kernel<<<pg, 256, 0, stream>>>(za, zb, slices, w, npart);
    dim3 sg(NSLICES, 2);
    sigreg_kernel<<<sg, 256, 0, stream>>>(w, out, npart);
}

// Round 7
// 103.724 us; speedup vs baseline: 1.1542x; 1.1542x over previous
//
#include <hip/hip_runtime.h>
#include <hip/hip_bf16.h>
#include <math.h>

#define NSLICES 1024
#define DIM     768
#define NPTS    256
#define K_REF   17
#define KSPLIT  8
#define KCHUNK  (DIM / KSPLIT)      // 96
#define XSZ     (NSLICES * NPTS)    // 262144 floats per (z, kchunk) partial

// ws float layout — every slot is fully rewritten every call (no zero-init needed)
#define INV_OFF 0                   // 192 partials
#define G_OFF   208                 // 17 scaled reference points
#define SIG_OFF 256                 // 2048 partials
#define XP_OFF  2560                // projection partials

#define EXP2(x) __builtin_amdgcn_exp2f(x)
// y = x * SCALE_A  =>  exp(-0.5(xi-xj)^2) == exp2(-(yi-yj)^2)
#define SCALE_A 0.84932180028801904272f      // sqrt(0.5 * log2(e))
#define INV_N2  1.52587890625e-05f           // 1/256^2
#define T2_SC   4.595588235294118e-4f        // 2/(256*17)

__device__ __forceinline__ float wave_sum(float v) {
#pragma unroll
    for (int o = 32; o; o >>= 1) v += __shfl_xor(v, o, 64);
    return v;
}

__device__ __forceinline__ float block_sum_256(float v, float* wred, int tid) {
    v = wave_sum(v);
    if ((tid & 63) == 0) wred[tid >> 6] = v;
    __syncthreads();
    float r = wred[0] + wred[1] + wred[2] + wred[3];
    __syncthreads();
    return r;
}

// ---------------- inv_loss partials + scaled reference points ---------------
__global__ __launch_bounds__(256) void inv_kernel(const float* __restrict__ za,
                                                  const float* __restrict__ zb,
                                                  float* __restrict__ w) {
    __shared__ float wred[4];
    int tid = threadIdx.x;
    int idx = blockIdx.x * 256 + tid;           // 192 blocks * 256 = 49152 float4s exactly
    const float4* A = (const float4*)za;
    const float4* B = (const float4*)zb;
    float4 a = A[idx], b = B[idx];
    float dx = a.x - b.x, dy = a.y - b.y, dz = a.z - b.z, dw = a.w - b.w;
    float p = dx * dx + dy * dy + dz * dz + dw * dw;
    float s = block_sum_256(p, wred, tid);
    if (tid == 0) w[INV_OFF + blockIdx.x] = s;
    if (blockIdx.x == 0 && tid < K_REF) {
        float q = 0.01f + 0.06125f * (float)tid;
        w[G_OFF + tid] = erfinvf(2.0f * q - 1.0f) * 1.41421356237309504880f * SCALE_A;
    }
}

// ---------------- projection GEMM: x[m][n] = dot(slices[m], z[n]) -----------
// (slice normalization dropped: standardization is scale-invariant per slice)
// grid: (4 n-tiles, 16 m-tiles, 2 z * KSPLIT k-chunks), block 256 = 16x16, 4x4/thread.
__global__ __launch_bounds__(256) void proj_kernel(const float* __restrict__ za,
                                                   const float* __restrict__ zb,
                                                   const float* __restrict__ slices,
                                                   float* __restrict__ w, int npart) {
    __shared__ float sA[16][68];
    __shared__ float sB[16][68];
    const int nt = blockIdx.x;            // 0..3
    const int mt = blockIdx.y;            // 0..15
    const int zi = blockIdx.z >> 3;       // 0..1
    const int kc = blockIdx.z & 7;        // 0..7
    const float* Z = zi ? zb : za;
    const int m0 = mt * 64, n0 = nt * 64;
    const int tid = threadIdx.x;
    const int tx = tid & 15, ty = tid >> 4;
    const int lr = tid >> 2, lq = tid & 3;      // loader: row 0..63, quad 0..3
    const int kbase = kc * KCHUNK;

    float acc[4][4] = {};

    for (int k0 = 0; k0 < KCHUNK; k0 += 16) {
        float4 av = *(const float4*)(slices + (size_t)(m0 + lr) * DIM + kbase + k0 + lq * 4);
        float4 bv = *(const float4*)(Z + (size_t)(n0 + lr) * DIM + kbase + k0 + lq * 4);
        // transposed store: sA[kk][m]
        sA[lq * 4 + 0][lr] = av.x; sA[lq * 4 + 1][lr] = av.y;
        sA[lq * 4 + 2][lr] = av.z; sA[lq * 4 + 3][lr] = av.w;
        sB[lq * 4 + 0][lr] = bv.x; sB[lq * 4 + 1][lr] = bv.y;
        sB[lq * 4 + 2][lr] = bv.z; sB[lq * 4 + 3][lr] = bv.w;
        __syncthreads();
#pragma unroll
        for (int kk = 0; kk < 16; ++kk) {
            float4 a = *(const float4*)&sA[kk][ty * 4];
            float4 b = *(const float4*)&sB[kk][tx * 4];
            acc[0][0] += a.x * b.x; acc[0][1] += a.x * b.y; acc[0][2] += a.x * b.z; acc[0][3] += a.x * b.w;
            acc[1][0] += a.y * b.x; acc[1][1] += a.y * b.y; acc[1][2] += a.y * b.z; acc[1][3] += a.y * b.w;
            acc[2][0] += a.z * b.x; acc[2][1] += a.z * b.y; acc[2][2] += a.z * b.z; acc[2][3] += a.z * b.w;
            acc[3][0] += a.w * b.x; acc[3][1] += a.w * b.y; acc[3][2] += a.w * b.z; acc[3][3] += a.w * b.w;
        }
        __syncthreads();
    }

    if (npart == KSPLIT) {
        float* X = w + XP_OFF + ((size_t)zi * KSPLIT + kc) * XSZ;
#pragma unroll
        for (int i = 0; i < 4; ++i) {
            float4 o; o.x = acc[i][0]; o.y = acc[i][1]; o.z = acc[i][2]; o.w = acc[i][3];
            *(float4*)(X + (size_t)(m0 + ty * 4 + i) * NPTS + n0 + tx * 4) = o;
        }
    } else {
        float* X = w + XP_OFF + (size_t)zi * XSZ;
#pragma unroll
        for (int i = 0; i < 4; ++i)
#pragma unroll
            for (int j = 0; j < 4; ++j)
                atomicAdd(X + (size_t)(m0 + ty * 4 + i) * NPTS + n0 + tx * 4 + j, acc[i][j]);
    }
}

// ---------------- per-slice sigreg (t1 + t2), broadcast-ILP -----------------
// Full 256-key loop per lane; keys read as uniform-address float4 (LDS broadcast,
// conflict-free), 4 independent accumulator chains, unroll 8 -> 32 exps in flight.
// grid: (NSLICES, 2); block 256 (one thread per sample point).
__global__ __launch_bounds__(256) void sigreg_kernel(float* __restrict__ w, int npart) {
    __shared__ __align__(16) float ys[NPTS];
    __shared__ float gsh[K_REF];
    __shared__ float wred[4];
    const int m = blockIdx.x;
    const int zi = blockIdx.y;
    const int tid = threadIdx.x;

    const float* Xb = w + XP_OFF + (size_t)zi * npart * XSZ + (size_t)m * NPTS + tid;
    float xv = 0.f;
    for (int p = 0; p < npart; ++p) xv += Xb[(size_t)p * XSZ];
    if (tid < K_REF) gsh[tid] = w[G_OFF + tid];

    float mu = block_sum_256(xv, wred, tid) * (1.0f / NPTS);
    float dv = xv - mu;
    float ss = block_sum_256(dv * dv, wred, tid);
    float sd = sqrtf(ss * (1.0f / (NPTS - 1))) + 1e-6f;
    float yv = (dv / sd) * SCALE_A;
    ys[tid] = yv;
    __syncthreads();

    float a0 = 0.f, a1 = 0.f, a2 = 0.f, a3 = 0.f;
#pragma unroll 8
    for (int j = 0; j < NPTS / 4; ++j) {
        float4 k = *(const float4*)&ys[4 * j];      // uniform addr -> broadcast
        float d0 = yv - k.x, d1 = yv - k.y, d2 = yv - k.z, d3 = yv - k.w;
        a0 += EXP2(-(d0 * d0));
        a1 += EXP2(-(d1 * d1));
        a2 += EXP2(-(d2 * d2));
        a3 += EXP2(-(d3 * d3));
    }
    float s1 = (a0 + a1) + (a2 + a3);               // includes diagonal, as t1 does
    float s2 = 0.f;
#pragma unroll
    for (int k = 0; k < K_REF; ++k) {
        float d = yv - gsh[k];
        s2 += EXP2(-(d * d));
    }
    float c = s1 * INV_N2 - s2 * T2_SC;
    float tot = block_sum_256(c, wred, tid);
    if (tid == 0) w[SIG_OFF + zi * NSLICES + m] = tot * (0.5f / (float)NSLICES);
}

// ---------------- final: reduce slots + t3 + combine ------------------------
__global__ __launch_bounds__(256) void final_kernel(const float* __restrict__ w,
                                                    float* __restrict__ out) {
    __shared__ float wred[4];
    __shared__ float gsh[K_REF];
    const int tid = threadIdx.x;
    if (tid < K_REF) gsh[tid] = w[G_OFF + tid];
    float sv = 0.f;
    for (int i = tid; i < 2 * NSLICES; i += 256) sv += w[SIG_OFF + i];
    float iv = (tid < 192) ? w[INV_OFF + tid] : 0.f;
    float sig = block_sum_256(sv, wred, tid);
    float inv = block_sum_256(iv, wred, tid);
    // t3 over 289 pairs, parallel (gsh already scaled by SCALE_A)
    float t3p = 0.f;
    for (int idx = tid; idx < K_REF * K_REF; idx += 256) {
        int k = idx / K_REF, l = idx - k * K_REF;
        float d = gsh[k] - gsh[l];
        t3p += EXP2(-(d * d));
    }
    float t3 = block_sum_256(t3p, wred, tid) * (1.0f / ((float)K_REF * (float)K_REF));
    if (tid == 0) {
        out[0] = 25.0f * inv * (1.0f / ((float)NPTS * (float)DIM))
               + 25.0f * (sig + t3);
    }
}

extern "C" void kernel_launch(void* const* d_in, const int* in_sizes, int n_in,
                              void* d_out, int out_size, void* d_ws, size_t ws_size,
                              hipStream_t stream) {
    const float* za = (const float*)d_in[0];
    const float* zb = (const float*)d_in[1];
    const float* slices = (const float*)d_in[2];
    float* out = (float*)d_out;
    float* w = (float*)d_ws;

    const size_t need_full = (size_t)(XP_OFF + 2 * KSPLIT * XSZ) * sizeof(float); // ~16.8 MB
    const int npart = (ws_size >= need_full) ? KSPLIT : 1;

    if (npart == 1)   // fallback only (harness ws is plenty; never taken)
        hipMemsetAsync(w + XP_OFF, 0, (size_t)2 * XSZ * sizeof(float), stream);

    inv_kernel<<<192, 256, 0, stream>>>(za, zb, w);
    dim3 pg(4, 16, 2 * KSPLIT);
    proj_kernel<<<pg, 256, 0, stream>>>(za, zb, slices, w, npart);
    dim3 sg(NSLICES, 2);
    sigreg_kernel<<<sg, 256, 0, stream>>>(w, npart);
    final_kernel<<<1, 256, 0, stream>>>(w, out);
}

// Round 9
// 97.910 us; speedup vs baseline: 1.2228x; 1.0594x over previous
//
#include <hip/hip_runtime.h>
#include <hip/hip_bf16.h>
#include <math.h>

#define NSLICES 1024
#define DIM     768
#define NPTS    256
#define K_REF   17
#define KSPLIT  8
#define KCHUNK  (DIM / KSPLIT)      // 96
#define XSZ     (NSLICES * NPTS)    // 262144 floats per (z, kchunk) partial

// ws float layout — every slot is fully rewritten every call (no zero-init needed)
#define INV_OFF 0                   // 192 partials
#define G_OFF   208                 // 17 scaled reference points
#define SIG_OFF 256                 // 2048 partials
#define XP_OFF  2560                // projection partials

#define EXP2(x) __builtin_amdgcn_exp2f(x)
// y = x * SCALE_A  =>  exp(-0.5(xi-xj)^2) == exp2(-(yi-yj)^2)
#define SCALE_A 0.84932180028801904272f      // sqrt(0.5 * log2(e))
#define INV_N2  1.52587890625e-05f           // 1/256^2
#define T2_SC   4.595588235294118e-4f        // 2/(256*17)

__device__ __forceinline__ float wave_sum(float v) {
#pragma unroll
    for (int o = 32; o; o >>= 1) v += __shfl_xor(v, o, 64);
    return v;
}

__device__ __forceinline__ float block_sum_256(float v, float* wred, int tid) {
    v = wave_sum(v);
    if ((tid & 63) == 0) wred[tid >> 6] = v;
    __syncthreads();
    float r = wred[0] + wred[1] + wred[2] + wred[3];
    __syncthreads();
    return r;
}

// ---------------- inv_loss partials + scaled reference points ---------------
__global__ __launch_bounds__(256) void inv_kernel(const float* __restrict__ za,
                                                  const float* __restrict__ zb,
                                                  float* __restrict__ w) {
    __shared__ float wred[4];
    int tid = threadIdx.x;
    int idx = blockIdx.x * 256 + tid;           // 192 blocks * 256 = 49152 float4s exactly
    const float4* A = (const float4*)za;
    const float4* B = (const float4*)zb;
    float4 a = A[idx], b = B[idx];
    float dx = a.x - b.x, dy = a.y - b.y, dz = a.z - b.z, dw = a.w - b.w;
    float p = dx * dx + dy * dy + dz * dz + dw * dw;
    float s = block_sum_256(p, wred, tid);
    if (tid == 0) w[INV_OFF + blockIdx.x] = s;
    if (blockIdx.x == 0 && tid < K_REF) {
        float q = 0.01f + 0.06125f * (float)tid;
        w[G_OFF + tid] = erfinvf(2.0f * q - 1.0f) * 1.41421356237309504880f * SCALE_A;
    }
}

// ---------------- projection GEMM: x[m][n] = dot(slices[m], z[n]) -----------
// (slice normalization dropped: standardization is scale-invariant per slice)
// grid: (4 n-tiles, 16 m-tiles, 2 z * KSPLIT k-chunks), block 256 = 16x16, 4x4/thread.
__global__ __launch_bounds__(256) void proj_kernel(const float* __restrict__ za,
                                                   const float* __restrict__ zb,
                                                   const float* __restrict__ slices,
                                                   float* __restrict__ w, int npart) {
    __shared__ float sA[16][68];
    __shared__ float sB[16][68];
    const int nt = blockIdx.x;            // 0..3
    const int mt = blockIdx.y;            // 0..15
    const int zi = blockIdx.z >> 3;       // 0..1
    const int kc = blockIdx.z & 7;        // 0..7
    const float* Z = zi ? zb : za;
    const int m0 = mt * 64, n0 = nt * 64;
    const int tid = threadIdx.x;
    const int tx = tid & 15, ty = tid >> 4;
    const int lr = tid >> 2, lq = tid & 3;      // loader: row 0..63, quad 0..3
    const int kbase = kc * KCHUNK;

    float acc[4][4] = {};

    for (int k0 = 0; k0 < KCHUNK; k0 += 16) {
        float4 av = *(const float4*)(slices + (size_t)(m0 + lr) * DIM + kbase + k0 + lq * 4);
        float4 bv = *(const float4*)(Z + (size_t)(n0 + lr) * DIM + kbase + k0 + lq * 4);
        // transposed store: sA[kk][m]
        sA[lq * 4 + 0][lr] = av.x; sA[lq * 4 + 1][lr] = av.y;
        sA[lq * 4 + 2][lr] = av.z; sA[lq * 4 + 3][lr] = av.w;
        sB[lq * 4 + 0][lr] = bv.x; sB[lq * 4 + 1][lr] = bv.y;
        sB[lq * 4 + 2][lr] = bv.z; sB[lq * 4 + 3][lr] = bv.w;
        __syncthreads();
#pragma unroll
        for (int kk = 0; kk < 16; ++kk) {
            float4 a = *(const float4*)&sA[kk][ty * 4];
            float4 b = *(const float4*)&sB[kk][tx * 4];
            acc[0][0] += a.x * b.x; acc[0][1] += a.x * b.y; acc[0][2] += a.x * b.z; acc[0][3] += a.x * b.w;
            acc[1][0] += a.y * b.x; acc[1][1] += a.y * b.y; acc[1][2] += a.y * b.z; acc[1][3] += a.y * b.w;
            acc[2][0] += a.z * b.x; acc[2][1] += a.z * b.y; acc[2][2] += a.z * b.z; acc[2][3] += a.z * b.w;
            acc[3][0] += a.w * b.x; acc[3][1] += a.w * b.y; acc[3][2] += a.w * b.z; acc[3][3] += a.w * b.w;
        }
        __syncthreads();
    }

    if (npart == KSPLIT) {
        float* X = w + XP_OFF + ((size_t)zi * KSPLIT + kc) * XSZ;
#pragma unroll
        for (int i = 0; i < 4; ++i) {
            float4 o; o.x = acc[i][0]; o.y = acc[i][1]; o.z = acc[i][2]; o.w = acc[i][3];
            *(float4*)(X + (size_t)(m0 + ty * 4 + i) * NPTS + n0 + tx * 4) = o;
        }
    } else {
        float* X = w + XP_OFF + (size_t)zi * XSZ;
#pragma unroll
        for (int i = 0; i < 4; ++i)
#pragma unroll
            for (int j = 0; j < 4; ++j)
                atomicAdd(X + (size_t)(m0 + ty * 4 + i) * NPTS + n0 + tx * 4 + j, acc[i][j]);
    }
}

// ---------------- per-slice sigreg (t1 + t2), symmetric-halved + ILP --------
// t1 off-diag via circular offsets o=1..128 (4 independent chains, full unroll,
// imm-offset ds_reads); NPART compile-time so the 8 X-partial loads issue together.
// Single-pass mean/var: ss = sum(x^2) - mu*sum(x).
// grid: (NSLICES, 2); block 256 (one thread per sample point).
template <int NPART>
__global__ __launch_bounds__(256) void sigreg_kernel(float* __restrict__ w) {
    __shared__ __align__(16) float ys[2 * NPTS];   // duplicated: reads base + imm offset
    __shared__ float gsh[K_REF];
    __shared__ float wredA[4], wredB[4];
    const int m = blockIdx.x;
    const int zi = blockIdx.y;
    const int tid = threadIdx.x;

    const float* Xb = w + XP_OFF + (size_t)zi * NPART * XSZ + (size_t)m * NPTS + tid;
    float xp[NPART];
#pragma unroll
    for (int p = 0; p < NPART; ++p) xp[p] = Xb[(size_t)p * XSZ];   // 8 loads in flight
    if (tid < K_REF) gsh[tid] = w[G_OFF + tid];
    float xv = 0.f;
#pragma unroll
    for (int p = 0; p < NPART; ++p) xv += xp[p];

    // one reduction round for both sum(x) and sum(x^2)
    float r1 = wave_sum(xv);
    float r2 = wave_sum(xv * xv);
    if ((tid & 63) == 0) { wredA[tid >> 6] = r1; wredB[tid >> 6] = r2; }
    __syncthreads();
    float sumx  = (wredA[0] + wredA[1]) + (wredA[2] + wredA[3]);
    float sumx2 = (wredB[0] + wredB[1]) + (wredB[2] + wredB[3]);
    float mu = sumx * (1.0f / NPTS);
    float ss = sumx2 - mu * sumx;                  // = sum((x-mu)^2), mu^2 << var here
    float sd = sqrtf(ss * (1.0f / (NPTS - 1))) + 1e-6f;
    float yv = (xv - mu) / sd * SCALE_A;
    ys[tid] = yv;
    ys[tid + NPTS] = yv;
    __syncthreads();

    float a0 = 0.f, a1 = 0.f, a2 = 0.f, a3 = 0.f;
#pragma unroll
    for (int t = 0; t < 32; ++t) {                 // o = 4t+1 .. 4t+4 (covers 1..128)
        float d0 = yv - ys[tid + 4 * t + 1];
        float d1 = yv - ys[tid + 4 * t + 2];
        float d2 = yv - ys[tid + 4 * t + 3];
        float d3 = yv - ys[tid + 4 * t + 4];
        a0 += EXP2(-(d0 * d0));
        a1 += EXP2(-(d1 * d1));
        a2 += EXP2(-(d2 * d2));
        a3 += EXP2(-(d3 * d3));
    }
    float dl = yv - ys[tid + 128];
    float s128 = EXP2(-(dl * dl));
    float sg = 0.f;
#pragma unroll
    for (int k = 0; k < K_REF; ++k) {
        float d = yv - gsh[k];
        sg += EXP2(-(d * d));
    }
    // off-diag = 2*sum(o=1..128) - S_128 ; diagonal N added at tid 0
    float c = (2.0f * ((a0 + a1) + (a2 + a3)) - s128) * INV_N2 - sg * T2_SC;
    if (tid == 0) c += (float)NPTS * INV_N2;
    float v = wave_sum(c);
    if ((tid & 63) == 0) wredA[tid >> 6] = v;      // safe: all reads were pre-barrier
    __syncthreads();
    if (tid == 0) {
        float tot = (wredA[0] + wredA[1]) + (wredA[2] + wredA[3]);
        w[SIG_OFF + zi * NSLICES + m] = tot * (0.5f / (float)NSLICES);
    }
}

// ---------------- final: reduce slots + t3 + combine ------------------------
__global__ __launch_bounds__(256) void final_kernel(const float* __restrict__ w,
                                                    float* __restrict__ out) {
    __shared__ float wred[4];
    __shared__ float gsh[K_REF];
    const int tid = threadIdx.x;
    if (tid < K_REF) gsh[tid] = w[G_OFF + tid];
    float sv = 0.f;
    for (int i = tid; i < 2 * NSLICES; i += 256) sv += w[SIG_OFF + i];
    float iv = (tid < 192) ? w[INV_OFF + tid] : 0.f;
    float sig = block_sum_256(sv, wred, tid);
    float inv = block_sum_256(iv, wred, tid);
    // t3 over 289 pairs, parallel (gsh already scaled by SCALE_A)
    float t3p = 0.f;
    for (int idx = tid; idx < K_REF * K_REF; idx += 256) {
        int k = idx / K_REF, l = idx - k * K_REF;
        float d = gsh[k] - gsh[l];
        t3p += EXP2(-(d * d));
    }
    float t3 = block_sum_256(t3p, wred, tid) * (1.0f / ((float)K_REF * (float)K_REF));
    if (tid == 0) {
        out[0] = 25.0f * inv * (1.0f / ((float)NPTS * (float)DIM))
               + 25.0f * (sig + t3);
    }
}

extern "C" void kernel_launch(void* const* d_in, const int* in_sizes, int n_in,
                              void* d_out, int out_size, void* d_ws, size_t ws_size,
                              hipStream_t stream) {
    const float* za = (const float*)d_in[0];
    const float* zb = (const float*)d_in[1];
    const float* slices = (const float*)d_in[2];
    float* out = (float*)d_out;
    float* w = (float*)d_ws;

    const size_t need_full = (size_t)(XP_OFF + 2 * KSPLIT * XSZ) * sizeof(float); // ~16.8 MB
    const int npart = (ws_size >= need_full) ? KSPLIT : 1;

    if (npart == 1)   // fallback only (harness ws is plenty; never taken)
        hipMemsetAsync(w + XP_OFF, 0, (size_t)2 * XSZ * sizeof(float), stream);

    inv_kernel<<<192, 256, 0, stream>>>(za, zb, w);
    dim3 pg(4, 16, 2 * KSPLIT);
    proj_kernel<<<pg, 256, 0, stream>>>(za, zb, slices, w, npart);
    dim3 sg(NSLICES, 2);
    if (npart == KSPLIT)
        sigreg_kernel<KSPLIT><<<sg, 256, 0, stream>>>(w);
    else
        sigreg_kernel<1><<<sg, 256, 0, stream>>>(w);
    final_kernel<<<1, 256, 0, stream>>>(w, out);
}

// Round 10
// 86.994 us; speedup vs baseline: 1.3762x; 1.1255x over previous
//
#include <hip/hip_runtime.h>
#include <hip/hip_bf16.h>
#include <math.h>

#define NSLICES 1024
#define DIM     768
#define NPTS    256
#define K_REF   17
#define KSPLIT  4
#define KCHUNK  (DIM / KSPLIT)      // 192
#define XSZ     (NSLICES * NPTS)    // 262144 floats per (z, kchunk) partial
#define LPITCH  200                 // LDS row pitch in bf16 (400B: aligned + spread)

// ws float layout — every slot is fully rewritten every call (no zero-init needed)
#define INV_OFF 0                   // 192 partials
#define G_OFF   208                 // 17 scaled reference points
#define SIG_OFF 256                 // 2048 partials
#define XP_OFF  2560                // projection partials

#define EXP2(x) __builtin_amdgcn_exp2f(x)
// y = x * SCALE_A  =>  exp(-0.5(xi-xj)^2) == exp2(-(yi-yj)^2)
#define SCALE_A 0.84932180028801904272f      // sqrt(0.5 * log2(e))
#define INV_N2  1.52587890625e-05f           // 1/256^2
#define T2_SC   4.595588235294118e-4f        // 2/(256*17)

typedef __attribute__((ext_vector_type(8))) short bf16x8_t;   // 8 bf16 = 4 VGPRs
typedef __attribute__((ext_vector_type(4))) float f32x4_t;    // MFMA accumulator

__device__ __forceinline__ float wave_sum(float v) {
#pragma unroll
    for (int o = 32; o; o >>= 1) v += __shfl_xor(v, o, 64);
    return v;
}

__device__ __forceinline__ float block_sum_256(float v, float* wred, int tid) {
    v = wave_sum(v);
    if ((tid & 63) == 0) wred[tid >> 6] = v;
    __syncthreads();
    float r = wred[0] + wred[1] + wred[2] + wred[3];
    __syncthreads();
    return r;
}

__device__ __forceinline__ unsigned f2bf(float f) {           // RNE f32->bf16
    unsigned u = __float_as_uint(f);
    return (u + 0x7FFFu + ((u >> 16) & 1u)) >> 16;
}

// ---------------- inv_loss partials + scaled reference points ---------------
__global__ __launch_bounds__(256) void inv_kernel(const float* __restrict__ za,
                                                  const float* __restrict__ zb,
                                                  float* __restrict__ w) {
    __shared__ float wred[4];
    int tid = threadIdx.x;
    int idx = blockIdx.x * 256 + tid;           // 192 blocks * 256 = 49152 float4s exactly
    const float4* A = (const float4*)za;
    const float4* B = (const float4*)zb;
    float4 a = A[idx], b = B[idx];
    float dx = a.x - b.x, dy = a.y - b.y, dz = a.z - b.z, dw = a.w - b.w;
    float p = dx * dx + dy * dy + dz * dz + dw * dw;
    float s = block_sum_256(p, wred, tid);
    if (tid == 0) w[INV_OFF + blockIdx.x] = s;
    if (blockIdx.x == 0 && tid < K_REF) {
        float q = 0.01f + 0.06125f * (float)tid;
        w[G_OFF + tid] = erfinvf(2.0f * q - 1.0f) * 1.41421356237309504880f * SCALE_A;
    }
}

// ---------------- projection GEMM via bf16 MFMA -----------------------------
// x[m][n] = dot(slices[m], z[n])  (slice normalization dropped: scale-invariant)
// 64x64 tile, 4 waves (2x2), KCHUNK=192 staged once as bf16, 6 MFMA K-steps.
// Fragment recipe per m91 gemm_bt: A row=lane&15, k=(lane>>4)*8+i; B^T same on
// z rows; C/D col=lane&15, row=(lane>>4)*4+reg.
// grid: (4 n-tiles, 16 m-tiles, 2 z * KSPLIT) = 512 blocks (2/CU).
__global__ __launch_bounds__(256) void proj_kernel(const float* __restrict__ za,
                                                   const float* __restrict__ zb,
                                                   const float* __restrict__ slices,
                                                   float* __restrict__ w, int npart) {
    __shared__ unsigned short lA[64][LPITCH];
    __shared__ unsigned short lB[64][LPITCH];
    const int nt = blockIdx.x;            // 0..3
    const int mt = blockIdx.y;            // 0..15
    const int zi = blockIdx.z >> 2;       // 0..1
    const int kc = blockIdx.z & 3;        // 0..3
    const float* Z = zi ? zb : za;
    const int m0 = mt * 64, n0 = nt * 64;
    const int tid = threadIdx.x;
    const int kbase = kc * KCHUNK;

    // ---- stage: 64 rows x 192 k, f32 -> bf16 ----
    {
        const int r = tid >> 2;           // 0..63
        const int c4 = tid & 3;           // float4 col group
        const float* Ap = slices + (size_t)(m0 + r) * DIM + kbase + c4 * 4;
        const float* Bp = Z + (size_t)(n0 + r) * DIM + kbase + c4 * 4;
        unsigned short* la = &lA[r][c4 * 4];
        unsigned short* lb = &lB[r][c4 * 4];
#pragma unroll
        for (int i = 0; i < 12; ++i) {
            float4 av = *(const float4*)(Ap + i * 16);
            float4 bv = *(const float4*)(Bp + i * 16);
            uint2 ap, bp;
            ap.x = f2bf(av.x) | (f2bf(av.y) << 16);
            ap.y = f2bf(av.z) | (f2bf(av.w) << 16);
            bp.x = f2bf(bv.x) | (f2bf(bv.y) << 16);
            bp.y = f2bf(bv.z) | (f2bf(bv.w) << 16);
            *(uint2*)(la + i * 16) = ap;
            *(uint2*)(lb + i * 16) = bp;
        }
    }
    __syncthreads();

    // ---- compute: 4 waves, each a 32x32 quadrant (2x2 of 16x16 MFMA tiles) ----
    const int wv = tid >> 6;
    const int wr = wv >> 1, wc = wv & 1;
    const int lane = tid & 63;
    const int fr = lane & 15, fq = lane >> 4;

    f32x4_t acc00 = {0.f, 0.f, 0.f, 0.f}, acc01 = acc00, acc10 = acc00, acc11 = acc00;
    const int ra0 = wr * 32 + fr, ra1 = ra0 + 16;
    const int rb0 = wc * 32 + fr, rb1 = rb0 + 16;
#pragma unroll
    for (int ks = 0; ks < KCHUNK / 32; ++ks) {
        const int k0 = ks * 32 + fq * 8;
        bf16x8_t a0 = *(const bf16x8_t*)&lA[ra0][k0];
        bf16x8_t a1 = *(const bf16x8_t*)&lA[ra1][k0];
        bf16x8_t b0 = *(const bf16x8_t*)&lB[rb0][k0];
        bf16x8_t b1 = *(const bf16x8_t*)&lB[rb1][k0];
        acc00 = __builtin_amdgcn_mfma_f32_16x16x32_bf16(a0, b0, acc00, 0, 0, 0);
        acc01 = __builtin_amdgcn_mfma_f32_16x16x32_bf16(a0, b1, acc01, 0, 0, 0);
        acc10 = __builtin_amdgcn_mfma_f32_16x16x32_bf16(a1, b0, acc10, 0, 0, 0);
        acc11 = __builtin_amdgcn_mfma_f32_16x16x32_bf16(a1, b1, acc11, 0, 0, 0);
    }

    // ---- C-write: row = base_m + fq*4 + j, col = base_n + fr ----
    const int rowB = m0 + wr * 32 + fq * 4;
    const int colB = n0 + wc * 32 + fr;
    if (npart == KSPLIT) {
        float* X = w + XP_OFF + ((size_t)zi * KSPLIT + kc) * XSZ;
#pragma unroll
        for (int j = 0; j < 4; ++j) {
            X[(size_t)(rowB + j) * NPTS + colB]           = acc00[j];
            X[(size_t)(rowB + j) * NPTS + colB + 16]      = acc01[j];
            X[(size_t)(rowB + 16 + j) * NPTS + colB]      = acc10[j];
            X[(size_t)(rowB + 16 + j) * NPTS + colB + 16] = acc11[j];
        }
    } else {
        float* X = w + XP_OFF + (size_t)zi * XSZ;
#pragma unroll
        for (int j = 0; j < 4; ++j) {
            atomicAdd(X + (size_t)(rowB + j) * NPTS + colB,           acc00[j]);
            atomicAdd(X + (size_t)(rowB + j) * NPTS + colB + 16,      acc01[j]);
            atomicAdd(X + (size_t)(rowB + 16 + j) * NPTS + colB,      acc10[j]);
            atomicAdd(X + (size_t)(rowB + 16 + j) * NPTS + colB + 16, acc11[j]);
        }
    }
}

// ---------------- per-slice sigreg (t1 + t2), symmetric-halved + ILP --------
// t1 off-diag via circular offsets o=1..128 (4 independent chains, full unroll,
// imm-offset ds_reads); NPART compile-time so the X-partial loads issue together.
// Single-pass mean/var: ss = sum(x^2) - mu*sum(x).
// grid: (NSLICES, 2); block 256 (one thread per sample point).
template <int NPART>
__global__ __launch_bounds__(256) void sigreg_kernel(float* __restrict__ w) {
    __shared__ __align__(16) float ys[2 * NPTS];   // duplicated: reads base + imm offset
    __shared__ float gsh[K_REF];
    __shared__ float wredA[4], wredB[4];
    const int m = blockIdx.x;
    const int zi = blockIdx.y;
    const int tid = threadIdx.x;

    const float* Xb = w + XP_OFF + (size_t)zi * NPART * XSZ + (size_t)m * NPTS + tid;
    float xp[NPART];
#pragma unroll
    for (int p = 0; p < NPART; ++p) xp[p] = Xb[(size_t)p * XSZ];   // loads in flight
    if (tid < K_REF) gsh[tid] = w[G_OFF + tid];
    float xv = 0.f;
#pragma unroll
    for (int p = 0; p < NPART; ++p) xv += xp[p];

    // one reduction round for both sum(x) and sum(x^2)
    float r1 = wave_sum(xv);
    float r2 = wave_sum(xv * xv);
    if ((tid & 63) == 0) { wredA[tid >> 6] = r1; wredB[tid >> 6] = r2; }
    __syncthreads();
    float sumx  = (wredA[0] + wredA[1]) + (wredA[2] + wredA[3]);
    float sumx2 = (wredB[0] + wredB[1]) + (wredB[2] + wredB[3]);
    float mu = sumx * (1.0f / NPTS);
    float ss = sumx2 - mu * sumx;                  // = sum((x-mu)^2), mu^2 << var here
    float sd = sqrtf(ss * (1.0f / (NPTS - 1))) + 1e-6f;
    float yv = (xv - mu) / sd * SCALE_A;
    ys[tid] = yv;
    ys[tid + NPTS] = yv;
    __syncthreads();

    float a0 = 0.f, a1 = 0.f, a2 = 0.f, a3 = 0.f;
#pragma unroll
    for (int t = 0; t < 32; ++t) {                 // o = 4t+1 .. 4t+4 (covers 1..128)
        float d0 = yv - ys[tid + 4 * t + 1];
        float d1 = yv - ys[tid + 4 * t + 2];
        float d2 = yv - ys[tid + 4 * t + 3];
        float d3 = yv - ys[tid + 4 * t + 4];
        a0 += EXP2(-(d0 * d0));
        a1 += EXP2(-(d1 * d1));
        a2 += EXP2(-(d2 * d2));
        a3 += EXP2(-(d3 * d3));
    }
    float dl = yv - ys[tid + 128];
    float s128 = EXP2(-(dl * dl));
    float sg = 0.f;
#pragma unroll
    for (int k = 0; k < K_REF; ++k) {
        float d = yv - gsh[k];
        sg += EXP2(-(d * d));
    }
    // off-diag = 2*sum(o=1..128) - S_128 ; diagonal N added at tid 0
    float c = (2.0f * ((a0 + a1) + (a2 + a3)) - s128) * INV_N2 - sg * T2_SC;
    if (tid == 0) c += (float)NPTS * INV_N2;
    float v = wave_sum(c);
    if ((tid & 63) == 0) wredA[tid >> 6] = v;      // safe: all reads were pre-barrier
    __syncthreads();
    if (tid == 0) {
        float tot = (wredA[0] + wredA[1]) + (wredA[2] + wredA[3]);
        w[SIG_OFF + zi * NSLICES + m] = tot * (0.5f / (float)NSLICES);
    }
}

// ---------------- final: reduce slots + t3 + combine ------------------------
__global__ __launch_bounds__(256) void final_kernel(const float* __restrict__ w,
                                                    float* __restrict__ out) {
    __shared__ float wred[4];
    __shared__ float gsh[K_REF];
    const int tid = threadIdx.x;
    if (tid < K_REF) gsh[tid] = w[G_OFF + tid];
    float sv = 0.f;
    for (int i = tid; i < 2 * NSLICES; i += 256) sv += w[SIG_OFF + i];
    float iv = (tid < 192) ? w[INV_OFF + tid] : 0.f;
    float sig = block_sum_256(sv, wred, tid);
    float inv = block_sum_256(iv, wred, tid);
    // t3 over 289 pairs, parallel (gsh already scaled by SCALE_A)
    float t3p = 0.f;
    for (int idx = tid; idx < K_REF * K_REF; idx += 256) {
        int k = idx / K_REF, l = idx - k * K_REF;
        float d = gsh[k] - gsh[l];
        t3p += EXP2(-(d * d));
    }
    float t3 = block_sum_256(t3p, wred, tid) * (1.0f / ((float)K_REF * (float)K_REF));
    if (tid == 0) {
        out[0] = 25.0f * inv * (1.0f / ((float)NPTS * (float)DIM))
               + 25.0f * (sig + t3);
    }
}

extern "C" void kernel_launch(void* const* d_in, const int* in_sizes, int n_in,
                              void* d_out, int out_size, void* d_ws, size_t ws_size,
                              hipStream_t stream) {
    const float* za = (const float*)d_in[0];
    const float* zb = (const float*)d_in[1];
    const float* slices = (const float*)d_in[2];
    float* out = (float*)d_out;
    float* w = (float*)d_ws;

    const size_t need_full = (size_t)(XP_OFF + 2 * KSPLIT * XSZ) * sizeof(float); // ~8.4 MB
    const int npart = (ws_size >= need_full) ? KSPLIT : 1;

    if (npart == 1)   // fallback only (harness ws is plenty; never taken)
        hipMemsetAsync(w + XP_OFF, 0, (size_t)2 * XSZ * sizeof(float), stream);

    inv_kernel<<<192, 256, 0, stream>>>(za, zb, w);
    dim3 pg(4, 16, 2 * KSPLIT);
    proj_kernel<<<pg, 256, 0, stream>>>(za, zb, slices, w, npart);
    dim3 sg(NSLICES, 2);
    if (npart == KSPLIT)
        sigreg_kernel<KSPLIT><<<sg, 256, 0, stream>>>(w);
    else
        sigreg_kernel<1><<<sg, 256, 0, stream>>>(w);
    final_kernel<<<1, 256, 0, stream>>>(w, out);
}

// Round 11
// 86.504 us; speedup vs baseline: 1.3840x; 1.0057x over previous
//
#include <hip/hip_runtime.h>
#include <hip/hip_bf16.h>
#include <math.h>

#define NSLICES 1024
#define DIM     768
#define NPTS    256
#define K_REF   17
#define KSPLIT  4
#define KCHUNK  (DIM / KSPLIT)      // 192
#define XSZ     (NSLICES * NPTS)    // 262144 floats per (z, kchunk) partial
#define LPITCH  200                 // LDS row pitch in bf16 (400B: aligned + spread)

// ws float layout — every slot is fully rewritten every call (no zero-init needed)
#define INV_OFF 0                   // 64 partials
#define G_OFF   208                 // 17 scaled reference points
#define SIG_OFF 256                 // 2048 partials
#define XP_OFF  2560                // projection partials

#define EXP2(x) __builtin_amdgcn_exp2f(x)
// y = x * SCALE_A  =>  exp(-0.5(xi-xj)^2) == exp2(-(yi-yj)^2)
#define SCALE_A 0.84932180028801904272f      // sqrt(0.5 * log2(e))
#define INV_N2  1.52587890625e-05f           // 1/256^2
#define T2_SC   4.595588235294118e-4f        // 2/(256*17)

typedef __attribute__((ext_vector_type(8))) short bf16x8_t;   // 8 bf16 = 4 VGPRs
typedef __attribute__((ext_vector_type(4))) float f32x4_t;    // MFMA accumulator

__device__ __forceinline__ float wave_sum(float v) {
#pragma unroll
    for (int o = 32; o; o >>= 1) v += __shfl_xor(v, o, 64);
    return v;
}

__device__ __forceinline__ float block_sum_256(float v, float* wred, int tid) {
    v = wave_sum(v);
    if ((tid & 63) == 0) wred[tid >> 6] = v;
    __syncthreads();
    float r = wred[0] + wred[1] + wred[2] + wred[3];
    __syncthreads();
    return r;
}

__device__ __forceinline__ unsigned f2bf(float f) {           // RNE f32->bf16
    unsigned u = __float_as_uint(f);
    return (u + 0x7FFFu + ((u >> 16) & 1u)) >> 16;
}

// ---------------- kernel 1: projection GEMM (bf16 MFMA) + fused inv ---------
// x[m][n] = dot(slices[m], z[n])  (slice normalization dropped: scale-invariant)
// grid: (4 n-tiles, 16 m-tiles, 2*KSPLIT + 1), block 256.
//  z < 2*KSPLIT : proj — 64x64 tile, 4 waves (2x2), KCHUNK=192 staged once as
//                 bf16, 6 MFMA K-steps (m91 gemm_bt fragment recipe).
//  z == 2*KSPLIT: 64 inv blocks (b = mt*4+nt); block 0 also writes scaled g.
__global__ __launch_bounds__(256) void proj_inv_kernel(const float* __restrict__ za,
                                                       const float* __restrict__ zb,
                                                       const float* __restrict__ slices,
                                                       float* __restrict__ w, int npart) {
    const int tid = threadIdx.x;

    if (blockIdx.z == 2 * KSPLIT) {
        // ---- inv path: 64 blocks * 256 threads * 3 float4 = 256*768 ----
        __shared__ float wred[4];
        const int b = blockIdx.y * 4 + blockIdx.x;      // 0..63
        const float4* A = (const float4*)za;
        const float4* B = (const float4*)zb;
        float p = 0.f;
#pragma unroll
        for (int i = 0; i < 3; ++i) {
            int idx = b * 768 + i * 256 + tid;
            float4 a = A[idx], bb = B[idx];
            float dx = a.x - bb.x, dy = a.y - bb.y, dz = a.z - bb.z, dw = a.w - bb.w;
            p += dx * dx + dy * dy + dz * dz + dw * dw;
        }
        float s = block_sum_256(p, wred, tid);
        if (tid == 0) w[INV_OFF + b] = s;
        if (b == 0 && tid < K_REF) {
            float q = 0.01f + 0.06125f * (float)tid;
            w[G_OFF + tid] = erfinvf(2.0f * q - 1.0f) * 1.41421356237309504880f * SCALE_A;
        }
        return;
    }

    // ---- proj path ----
    __shared__ unsigned short lA[64][LPITCH];
    __shared__ unsigned short lB[64][LPITCH];
    const int nt = blockIdx.x;            // 0..3
    const int mt = blockIdx.y;            // 0..15
    const int zi = blockIdx.z >> 2;       // 0..1
    const int kc = blockIdx.z & 3;        // 0..3
    const float* Z = zi ? zb : za;
    const int m0 = mt * 64, n0 = nt * 64;
    const int kbase = kc * KCHUNK;

    // stage: 64 rows x 192 k, f32 -> bf16
    {
        const int r = tid >> 2;           // 0..63
        const int c4 = tid & 3;           // float4 col group
        const float* Ap = slices + (size_t)(m0 + r) * DIM + kbase + c4 * 4;
        const float* Bp = Z + (size_t)(n0 + r) * DIM + kbase + c4 * 4;
        unsigned short* la = &lA[r][c4 * 4];
        unsigned short* lb = &lB[r][c4 * 4];
#pragma unroll
        for (int i = 0; i < 12; ++i) {
            float4 av = *(const float4*)(Ap + i * 16);
            float4 bv = *(const float4*)(Bp + i * 16);
            uint2 ap, bp;
            ap.x = f2bf(av.x) | (f2bf(av.y) << 16);
            ap.y = f2bf(av.z) | (f2bf(av.w) << 16);
            bp.x = f2bf(bv.x) | (f2bf(bv.y) << 16);
            bp.y = f2bf(bv.z) | (f2bf(bv.w) << 16);
            *(uint2*)(la + i * 16) = ap;
            *(uint2*)(lb + i * 16) = bp;
        }
    }
    __syncthreads();

    // compute: 4 waves, each a 32x32 quadrant (2x2 of 16x16 MFMA tiles)
    const int wv = tid >> 6;
    const int wr = wv >> 1, wc = wv & 1;
    const int lane = tid & 63;
    const int fr = lane & 15, fq = lane >> 4;

    f32x4_t acc00 = {0.f, 0.f, 0.f, 0.f}, acc01 = acc00, acc10 = acc00, acc11 = acc00;
    const int ra0 = wr * 32 + fr, ra1 = ra0 + 16;
    const int rb0 = wc * 32 + fr, rb1 = rb0 + 16;
#pragma unroll
    for (int ks = 0; ks < KCHUNK / 32; ++ks) {
        const int k0 = ks * 32 + fq * 8;
        bf16x8_t a0 = *(const bf16x8_t*)&lA[ra0][k0];
        bf16x8_t a1 = *(const bf16x8_t*)&lA[ra1][k0];
        bf16x8_t b0 = *(const bf16x8_t*)&lB[rb0][k0];
        bf16x8_t b1 = *(const bf16x8_t*)&lB[rb1][k0];
        acc00 = __builtin_amdgcn_mfma_f32_16x16x32_bf16(a0, b0, acc00, 0, 0, 0);
        acc01 = __builtin_amdgcn_mfma_f32_16x16x32_bf16(a0, b1, acc01, 0, 0, 0);
        acc10 = __builtin_amdgcn_mfma_f32_16x16x32_bf16(a1, b0, acc10, 0, 0, 0);
        acc11 = __builtin_amdgcn_mfma_f32_16x16x32_bf16(a1, b1, acc11, 0, 0, 0);
    }

    // C-write: row = base_m + fq*4 + j, col = base_n + fr
    const int rowB = m0 + wr * 32 + fq * 4;
    const int colB = n0 + wc * 32 + fr;
    if (npart == KSPLIT) {
        float* X = w + XP_OFF + ((size_t)zi * KSPLIT + kc) * XSZ;
#pragma unroll
        for (int j = 0; j < 4; ++j) {
            X[(size_t)(rowB + j) * NPTS + colB]           = acc00[j];
            X[(size_t)(rowB + j) * NPTS + colB + 16]      = acc01[j];
            X[(size_t)(rowB + 16 + j) * NPTS + colB]      = acc10[j];
            X[(size_t)(rowB + 16 + j) * NPTS + colB + 16] = acc11[j];
        }
    } else {
        float* X = w + XP_OFF + (size_t)zi * XSZ;
#pragma unroll
        for (int j = 0; j < 4; ++j) {
            atomicAdd(X + (size_t)(rowB + j) * NPTS + colB,           acc00[j]);
            atomicAdd(X + (size_t)(rowB + j) * NPTS + colB + 16,      acc01[j]);
            atomicAdd(X + (size_t)(rowB + 16 + j) * NPTS + colB,      acc10[j]);
            atomicAdd(X + (size_t)(rowB + 16 + j) * NPTS + colB + 16, acc11[j]);
        }
    }
}

// ---------------- per-slice sigreg (t1 + t2), symmetric-halved + ILP --------
// t1 off-diag via circular offsets o=1..128 (4 independent chains, full unroll,
// imm-offset ds_reads); NPART compile-time so the X-partial loads issue together.
// Single-pass mean/var: ss = sum(x^2) - mu*sum(x).
// grid: (NSLICES, 2); block 256 (one thread per sample point).
template <int NPART>
__global__ __launch_bounds__(256) void sigreg_kernel(float* __restrict__ w) {
    __shared__ __align__(16) float ys[2 * NPTS];   // duplicated: reads base + imm offset
    __shared__ float gsh[K_REF];
    __shared__ float wredA[4], wredB[4];
    const int m = blockIdx.x;
    const int zi = blockIdx.y;
    const int tid = threadIdx.x;

    const float* Xb = w + XP_OFF + (size_t)zi * NPART * XSZ + (size_t)m * NPTS + tid;
    float xp[NPART];
#pragma unroll
    for (int p = 0; p < NPART; ++p) xp[p] = Xb[(size_t)p * XSZ];   // loads in flight
    if (tid < K_REF) gsh[tid] = w[G_OFF + tid];
    float xv = 0.f;
#pragma unroll
    for (int p = 0; p < NPART; ++p) xv += xp[p];

    // one reduction round for both sum(x) and sum(x^2)
    float r1 = wave_sum(xv);
    float r2 = wave_sum(xv * xv);
    if ((tid & 63) == 0) { wredA[tid >> 6] = r1; wredB[tid >> 6] = r2; }
    __syncthreads();
    float sumx  = (wredA[0] + wredA[1]) + (wredA[2] + wredA[3]);
    float sumx2 = (wredB[0] + wredB[1]) + (wredB[2] + wredB[3]);
    float mu = sumx * (1.0f / NPTS);
    float ss = sumx2 - mu * sumx;                  // = sum((x-mu)^2), mu^2 << var here
    float sd = sqrtf(ss * (1.0f / (NPTS - 1))) + 1e-6f;
    float yv = (xv - mu) / sd * SCALE_A;
    ys[tid] = yv;
    ys[tid + NPTS] = yv;
    __syncthreads();

    float a0 = 0.f, a1 = 0.f, a2 = 0.f, a3 = 0.f;
#pragma unroll
    for (int t = 0; t < 32; ++t) {                 // o = 4t+1 .. 4t+4 (covers 1..128)
        float d0 = yv - ys[tid + 4 * t + 1];
        float d1 = yv - ys[tid + 4 * t + 2];
        float d2 = yv - ys[tid + 4 * t + 3];
        float d3 = yv - ys[tid + 4 * t + 4];
        a0 += EXP2(-(d0 * d0));
        a1 += EXP2(-(d1 * d1));
        a2 += EXP2(-(d2 * d2));
        a3 += EXP2(-(d3 * d3));
    }
    float dl = yv - ys[tid + 128];
    float s128 = EXP2(-(dl * dl));
    float sg = 0.f;
#pragma unroll
    for (int k = 0; k < K_REF; ++k) {
        float d = yv - gsh[k];
        sg += EXP2(-(d * d));
    }
    // off-diag = 2*sum(o=1..128) - S_128 ; diagonal N added at tid 0
    float c = (2.0f * ((a0 + a1) + (a2 + a3)) - s128) * INV_N2 - sg * T2_SC;
    if (tid == 0) c += (float)NPTS * INV_N2;
    float v = wave_sum(c);
    if ((tid & 63) == 0) wredA[tid >> 6] = v;      // safe: all reads were pre-barrier
    __syncthreads();
    if (tid == 0) {
        float tot = (wredA[0] + wredA[1]) + (wredA[2] + wredA[3]);
        w[SIG_OFF + zi * NSLICES + m] = tot * (0.5f / (float)NSLICES);
    }
}

// ---------------- final: reduce slots + t3 + combine ------------------------
__global__ __launch_bounds__(256) void final_kernel(const float* __restrict__ w,
                                                    float* __restrict__ out) {
    __shared__ float wred[4];
    __shared__ float gsh[K_REF];
    const int tid = threadIdx.x;
    if (tid < K_REF) gsh[tid] = w[G_OFF + tid];
    float sv = 0.f;
    for (int i = tid; i < 2 * NSLICES; i += 256) sv += w[SIG_OFF + i];
    float iv = (tid < 64) ? w[INV_OFF + tid] : 0.f;
    float sig = block_sum_256(sv, wred, tid);
    float inv = block_sum_256(iv, wred, tid);
    // t3 over 289 pairs, parallel (gsh already scaled by SCALE_A)
    float t3p = 0.f;
    for (int idx = tid; idx < K_REF * K_REF; idx += 256) {
        int k = idx / K_REF, l = idx - k * K_REF;
        float d = gsh[k] - gsh[l];
        t3p += EXP2(-(d * d));
    }
    float t3 = block_sum_256(t3p, wred, tid) * (1.0f / ((float)K_REF * (float)K_REF));
    if (tid == 0) {
        out[0] = 25.0f * inv * (1.0f / ((float)NPTS * (float)DIM))
               + 25.0f * (sig + t3);
    }
}

extern "C" void kernel_launch(void* const* d_in, const int* in_sizes, int n_in,
                              void* d_out, int out_size, void* d_ws, size_t ws_size,
                              hipStream_t stream) {
    const float* za = (const float*)d_in[0];
    const float* zb = (const float*)d_in[1];
    const float* slices = (const float*)d_in[2];
    float* out = (float*)d_out;
    float* w = (float*)d_ws;

    const size_t need_full = (size_t)(XP_OFF + 2 * KSPLIT * XSZ) * sizeof(float); // ~8.4 MB
    const int npart = (ws_size >= need_full) ? KSPLIT : 1;

    if (npart == 1)   // fallback only (harness ws is plenty; never taken)
        hipMemsetAsync(w + XP_OFF, 0, (size_t)2 * XSZ * sizeof(float), stream);

    dim3 pg(4, 16, 2 * KSPLIT + 1);
    proj_inv_kernel<<<pg, 256, 0, stream>>>(za, zb, slices, w, npart);
    dim3 sg(NSLICES, 2);
    if (npart == KSPLIT)
        sigreg_kernel<KSPLIT><<<sg, 256, 0, stream>>>(w);
    else
        sigreg_kernel<1><<<sg, 256, 0, stream>>>(w);
    final_kernel<<<1, 256, 0, stream>>>(w, out);
}

// Round 12
// 83.390 us; speedup vs baseline: 1.4357x; 1.0373x over previous
//
#include <hip/hip_runtime.h>
#include <hip/hip_bf16.h>
#include <math.h>

#define NSLICES 1024
#define DIM     768
#define NPTS    256
#define K_REF   17
#define KSPLIT  4
#define KCHUNK  (DIM / KSPLIT)      // 192
#define XSZ     (NSLICES * NPTS)    // 262144 floats per (z, kchunk) partial
#define LPITCH  200                 // LDS row pitch in bf16 (400B: aligned + spread)

// ws float layout — every slot is fully rewritten every call (no zero-init needed)
#define INV_OFF 0                   // 64 partials
#define G_OFF   208                 // 17 scaled reference points
#define SIG_OFF 256                 // 2048 partials
#define XP_OFF  2560                // projection partials

#define EXP2(x) __builtin_amdgcn_exp2f(x)
// y = x * SCALE_A  =>  exp(-0.5(xi-xj)^2) == exp2(-(yi-yj)^2)
#define SCALE_A 0.84932180028801904272f      // sqrt(0.5 * log2(e))
#define INV_N2  1.52587890625e-05f           // 1/256^2
#define T2_SC   4.595588235294118e-4f        // 2/(256*17)

typedef __attribute__((ext_vector_type(8))) short bf16x8_t;   // 8 bf16 = 4 VGPRs
typedef __attribute__((ext_vector_type(4))) float f32x4_t;    // MFMA accumulator

__device__ __forceinline__ float wave_sum(float v) {
#pragma unroll
    for (int o = 32; o; o >>= 1) v += __shfl_xor(v, o, 64);
    return v;
}

__device__ __forceinline__ float block_sum_256(float v, float* wred, int tid) {
    v = wave_sum(v);
    if ((tid & 63) == 0) wred[tid >> 6] = v;
    __syncthreads();
    float r = wred[0] + wred[1] + wred[2] + wred[3];
    __syncthreads();
    return r;
}

__device__ __forceinline__ unsigned f2bf(float f) {           // RNE f32->bf16
    unsigned u = __float_as_uint(f);
    return (u + 0x7FFFu + ((u >> 16) & 1u)) >> 16;
}

// ---------------- kernel 1: projection GEMM (bf16 MFMA) + fused inv ---------
// x[m][n] = dot(slices[m], z[n])  (slice normalization dropped: scale-invariant)
// grid: (4 n-tiles, 16 m-tiles, 2*KSPLIT + 1), block 256.
//  z < 2*KSPLIT : proj — 64x64 tile, 4 waves (2x2), KCHUNK=192 staged once as
//                 bf16, 6 MFMA K-steps (m91 gemm_bt fragment recipe).
//  z == 2*KSPLIT: 64 inv blocks (b = mt*4+nt); block 0 also writes scaled g.
__global__ __launch_bounds__(256) void proj_inv_kernel(const float* __restrict__ za,
                                                       const float* __restrict__ zb,
                                                       const float* __restrict__ slices,
                                                       float* __restrict__ w, int npart) {
    const int tid = threadIdx.x;

    if (blockIdx.z == 2 * KSPLIT) {
        // ---- inv path: 64 blocks * 256 threads * 3 float4 = 256*768 ----
        __shared__ float wred[4];
        const int b = blockIdx.y * 4 + blockIdx.x;      // 0..63
        const float4* A = (const float4*)za;
        const float4* B = (const float4*)zb;
        float p = 0.f;
#pragma unroll
        for (int i = 0; i < 3; ++i) {
            int idx = b * 768 + i * 256 + tid;
            float4 a = A[idx], bb = B[idx];
            float dx = a.x - bb.x, dy = a.y - bb.y, dz = a.z - bb.z, dw = a.w - bb.w;
            p += dx * dx + dy * dy + dz * dz + dw * dw;
        }
        float s = block_sum_256(p, wred, tid);
        if (tid == 0) w[INV_OFF + b] = s;
        if (b == 0 && tid < K_REF) {
            float q = 0.01f + 0.06125f * (float)tid;
            w[G_OFF + tid] = erfinvf(2.0f * q - 1.0f) * 1.41421356237309504880f * SCALE_A;
        }
        return;
    }

    // ---- proj path ----
    __shared__ unsigned short lA[64][LPITCH];
    __shared__ unsigned short lB[64][LPITCH];
    const int nt = blockIdx.x;            // 0..3
    const int mt = blockIdx.y;            // 0..15
    const int zi = blockIdx.z >> 2;       // 0..1
    const int kc = blockIdx.z & 3;        // 0..3
    const float* Z = zi ? zb : za;
    const int m0 = mt * 64, n0 = nt * 64;
    const int kbase = kc * KCHUNK;

    // stage: 64 rows x 192 k, f32 -> bf16
    {
        const int r = tid >> 2;           // 0..63
        const int c4 = tid & 3;           // float4 col group
        const float* Ap = slices + (size_t)(m0 + r) * DIM + kbase + c4 * 4;
        const float* Bp = Z + (size_t)(n0 + r) * DIM + kbase + c4 * 4;
        unsigned short* la = &lA[r][c4 * 4];
        unsigned short* lb = &lB[r][c4 * 4];
#pragma unroll
        for (int i = 0; i < 12; ++i) {
            float4 av = *(const float4*)(Ap + i * 16);
            float4 bv = *(const float4*)(Bp + i * 16);
            uint2 ap, bp;
            ap.x = f2bf(av.x) | (f2bf(av.y) << 16);
            ap.y = f2bf(av.z) | (f2bf(av.w) << 16);
            bp.x = f2bf(bv.x) | (f2bf(bv.y) << 16);
            bp.y = f2bf(bv.z) | (f2bf(bv.w) << 16);
            *(uint2*)(la + i * 16) = ap;
            *(uint2*)(lb + i * 16) = bp;
        }
    }
    __syncthreads();

    // compute: 4 waves, each a 32x32 quadrant (2x2 of 16x16 MFMA tiles)
    const int wv = tid >> 6;
    const int wr = wv >> 1, wc = wv & 1;
    const int lane = tid & 63;
    const int fr = lane & 15, fq = lane >> 4;

    f32x4_t acc00 = {0.f, 0.f, 0.f, 0.f}, acc01 = acc00, acc10 = acc00, acc11 = acc00;
    const int ra0 = wr * 32 + fr, ra1 = ra0 + 16;
    const int rb0 = wc * 32 + fr, rb1 = rb0 + 16;
#pragma unroll
    for (int ks = 0; ks < KCHUNK / 32; ++ks) {
        const int k0 = ks * 32 + fq * 8;
        bf16x8_t a0 = *(const bf16x8_t*)&lA[ra0][k0];
        bf16x8_t a1 = *(const bf16x8_t*)&lA[ra1][k0];
        bf16x8_t b0 = *(const bf16x8_t*)&lB[rb0][k0];
        bf16x8_t b1 = *(const bf16x8_t*)&lB[rb1][k0];
        acc00 = __builtin_amdgcn_mfma_f32_16x16x32_bf16(a0, b0, acc00, 0, 0, 0);
        acc01 = __builtin_amdgcn_mfma_f32_16x16x32_bf16(a0, b1, acc01, 0, 0, 0);
        acc10 = __builtin_amdgcn_mfma_f32_16x16x32_bf16(a1, b0, acc10, 0, 0, 0);
        acc11 = __builtin_amdgcn_mfma_f32_16x16x32_bf16(a1, b1, acc11, 0, 0, 0);
    }

    // C-write: row = base_m + fq*4 + j, col = base_n + fr
    const int rowB = m0 + wr * 32 + fq * 4;
    const int colB = n0 + wc * 32 + fr;
    if (npart == KSPLIT) {
        float* X = w + XP_OFF + ((size_t)zi * KSPLIT + kc) * XSZ;
#pragma unroll
        for (int j = 0; j < 4; ++j) {
            X[(size_t)(rowB + j) * NPTS + colB]           = acc00[j];
            X[(size_t)(rowB + j) * NPTS + colB + 16]      = acc01[j];
            X[(size_t)(rowB + 16 + j) * NPTS + colB]      = acc10[j];
            X[(size_t)(rowB + 16 + j) * NPTS + colB + 16] = acc11[j];
        }
    } else {
        float* X = w + XP_OFF + (size_t)zi * XSZ;
#pragma unroll
        for (int j = 0; j < 4; ++j) {
            atomicAdd(X + (size_t)(rowB + j) * NPTS + colB,           acc00[j]);
            atomicAdd(X + (size_t)(rowB + j) * NPTS + colB + 16,      acc01[j]);
            atomicAdd(X + (size_t)(rowB + 16 + j) * NPTS + colB,      acc10[j]);
            atomicAdd(X + (size_t)(rowB + 16 + j) * NPTS + colB + 16, acc11[j]);
        }
    }
}

// ---------------- per-slice sigreg (t1 + t2), factored-exp form -------------
// exp2(-(yv-yj)^2) = exp2(-yv^2) * exp2(fma(2yv, yj, -yj^2)); LDS holds
// (yj, -yj^2) float2 pairs -> inner loop is 1 fma + 1 exp + 1 add per key.
// t1 off-diag via circular offsets o=1..128: total = 2*sum - S_128 (+ diag N).
// grid: (NSLICES, 2); block 256 (one thread per sample point).
template <int NPART>
__global__ __launch_bounds__(256) void sigreg_kernel(float* __restrict__ w) {
    __shared__ float2 ys2[2 * NPTS];   // duplicated (y, -y^2): base + imm offset reads
    __shared__ float2 gsh2[K_REF];
    __shared__ float wredA[4], wredB[4];
    const int m = blockIdx.x;
    const int zi = blockIdx.y;
    const int tid = threadIdx.x;

    const float* Xb = w + XP_OFF + (size_t)zi * NPART * XSZ + (size_t)m * NPTS + tid;
    float xp[NPART];
#pragma unroll
    for (int p = 0; p < NPART; ++p) xp[p] = Xb[(size_t)p * XSZ];   // loads in flight
    if (tid < K_REF) {
        float gv = w[G_OFF + tid];
        gsh2[tid] = make_float2(gv, -gv * gv);
    }
    float xv = 0.f;
#pragma unroll
    for (int p = 0; p < NPART; ++p) xv += xp[p];

    // one reduction round for both sum(x) and sum(x^2)
    float r1 = wave_sum(xv);
    float r2 = wave_sum(xv * xv);
    if ((tid & 63) == 0) { wredA[tid >> 6] = r1; wredB[tid >> 6] = r2; }
    __syncthreads();
    float sumx  = (wredA[0] + wredA[1]) + (wredA[2] + wredA[3]);
    float sumx2 = (wredB[0] + wredB[1]) + (wredB[2] + wredB[3]);
    float mu = sumx * (1.0f / NPTS);
    float ss = sumx2 - mu * sumx;                  // = sum((x-mu)^2), mu^2 << var here
    float sd = sqrtf(ss * (1.0f / (NPTS - 1))) + 1e-6f;
    float yv = (xv - mu) / sd * SCALE_A;
    float2 pr = make_float2(yv, -yv * yv);
    ys2[tid] = pr;
    ys2[tid + NPTS] = pr;
    __syncthreads();

    const float av = 2.0f * yv;
    float a0 = 0.f, a1 = 0.f, a2 = 0.f, a3 = 0.f;
#pragma unroll
    for (int t = 0; t < 32; ++t) {                 // o = 4t+1 .. 4t+4 (covers 1..128)
        float2 k1 = ys2[tid + 4 * t + 1];
        float2 k2 = ys2[tid + 4 * t + 2];
        float2 k3 = ys2[tid + 4 * t + 3];
        float2 k4 = ys2[tid + 4 * t + 4];
        a0 += EXP2(fmaf(av, k1.x, k1.y));
        a1 += EXP2(fmaf(av, k2.x, k2.y));
        a2 += EXP2(fmaf(av, k3.x, k3.y));
        a3 += EXP2(fmaf(av, k4.x, k4.y));
    }
    float fac = EXP2(-yv * yv);
    float s1 = ((a0 + a1) + (a2 + a3)) * fac;      // sum over o=1..128
    float dl = yv - ys2[tid + 128].x;
    float s128 = EXP2(-(dl * dl));
    float sg = 0.f;
#pragma unroll
    for (int k = 0; k < K_REF; ++k) {
        float2 g = gsh2[k];
        sg += EXP2(fmaf(av, g.x, g.y));
    }
    sg *= fac;
    // off-diag = 2*sum(o=1..128) - S_128 ; diagonal N added at tid 0
    float c = (2.0f * s1 - s128) * INV_N2 - sg * T2_SC;
    if (tid == 0) c += (float)NPTS * INV_N2;
    float v = wave_sum(c);
    if ((tid & 63) == 0) wredA[tid >> 6] = v;      // safe: all reads were pre-barrier
    __syncthreads();
    if (tid == 0) {
        float tot = (wredA[0] + wredA[1]) + (wredA[2] + wredA[3]);
        w[SIG_OFF + zi * NSLICES + m] = tot * (0.5f / (float)NSLICES);
    }
}

// ---------------- final: reduce slots + t3 + combine ------------------------
__global__ __launch_bounds__(256) void final_kernel(const float* __restrict__ w,
                                                    float* __restrict__ out) {
    __shared__ float wred[4];
    __shared__ float gsh[K_REF];
    const int tid = threadIdx.x;
    if (tid < K_REF) gsh[tid] = w[G_OFF + tid];
    float sv = 0.f;
    for (int i = tid; i < 2 * NSLICES; i += 256) sv += w[SIG_OFF + i];
    float iv = (tid < 64) ? w[INV_OFF + tid] : 0.f;
    float sig = block_sum_256(sv, wred, tid);
    float inv = block_sum_256(iv, wred, tid);
    // t3 over 289 pairs, parallel (gsh already scaled by SCALE_A)
    float t3p = 0.f;
    for (int idx = tid; idx < K_REF * K_REF; idx += 256) {
        int k = idx / K_REF, l = idx - k * K_REF;
        float d = gsh[k] - gsh[l];
        t3p += EXP2(-(d * d));
    }
    float t3 = block_sum_256(t3p, wred, tid) * (1.0f / ((float)K_REF * (float)K_REF));
    if (tid == 0) {
        out[0] = 25.0f * inv * (1.0f / ((float)NPTS * (float)DIM))
               + 25.0f * (sig + t3);
    }
}

extern "C" void kernel_launch(void* const* d_in, const int* in_sizes, int n_in,
                              void* d_out, int out_size, void* d_ws, size_t ws_size,
                              hipStream_t stream) {
    const float* za = (const float*)d_in[0];
    const float* zb = (const float*)d_in[1];
    const float* slices = (const float*)d_in[2];
    float* out = (float*)d_out;
    float* w = (float*)d_ws;

    const size_t need_full = (size_t)(XP_OFF + 2 * KSPLIT * XSZ) * sizeof(float); // ~8.4 MB
    const int npart = (ws_size >= need_full) ? KSPLIT : 1;

    if (npart == 1)   // fallback only (harness ws is plenty; never taken)
        hipMemsetAsync(w + XP_OFF, 0, (size_t)2 * XSZ * sizeof(float), stream);

    dim3 pg(4, 16, 2 * KSPLIT + 1);
    proj_inv_kernel<<<pg, 256, 0, stream>>>(za, zb, slices, w, npart);
    dim3 sg(NSLICES, 2);
    if (npart == KSPLIT)
        sigreg_kernel<KSPLIT><<<sg, 256, 0, stream>>>(w);
    else
        sigreg_kernel<1><<<sg, 256, 0, stream>>>(w);
    final_kernel<<<1, 256, 0, stream>>>(w, out);
}

// Round 13
// 80.917 us; speedup vs baseline: 1.4795x; 1.0306x over previous
//
#include <hip/hip_runtime.h>
#include <hip/hip_bf16.h>
#include <math.h>

#define NSLICES 1024
#define DIM     768
#define NPTS    256
#define K_REF   17
#define KSPLIT  4
#define KCHUNK  (DIM / KSPLIT)      // 192
#define XSZ     (NSLICES * NPTS)    // 262144 floats per (z, kchunk) partial
#define LPITCH  200                 // LDS row pitch in bf16 (400B: aligned + spread)

// ws float layout — every slot is fully rewritten every call (no zero-init needed)
#define INV_OFF 0                   // 64 partials
#define G_OFF   208                 // 17 scaled reference points
#define SIG_OFF 256                 // 2048 partials
#define XP_OFF  2560                // projection partials

#define EXP2(x) __builtin_amdgcn_exp2f(x)
// y = x * SCALE_A  =>  exp(-0.5(xi-xj)^2) == exp2(-(yi-yj)^2)
#define SCALE_A 0.84932180028801904272f      // sqrt(0.5 * log2(e))
#define INV_N2  1.52587890625e-05f           // 1/256^2
#define T2_SC   4.595588235294118e-4f        // 2/(256*17)

typedef __attribute__((ext_vector_type(8))) short bf16x8_t;   // 8 bf16 = 4 VGPRs
typedef __attribute__((ext_vector_type(4))) float f32x4_t;    // MFMA accumulator

__device__ __forceinline__ float wave_sum(float v) {
#pragma unroll
    for (int o = 32; o; o >>= 1) v += __shfl_xor(v, o, 64);
    return v;
}

__device__ __forceinline__ float block_sum_256(float v, float* wred, int tid) {
    v = wave_sum(v);
    if ((tid & 63) == 0) wred[tid >> 6] = v;
    __syncthreads();
    float r = wred[0] + wred[1] + wred[2] + wred[3];
    __syncthreads();
    return r;
}

__device__ __forceinline__ unsigned pkbf(float lo, float hi) {  // v_cvt_pk_bf16_f32
    union { __hip_bfloat162 h2; unsigned u; } c;
    c.h2 = __float22bfloat162_rn(make_float2(lo, hi));
    return c.u;
}

// ---------------- kernel 1: projection GEMM (bf16 MFMA) + fused inv ---------
// x[m][n] = dot(slices[m], z[n])  (slice normalization dropped: scale-invariant)
// grid: (4 n-tiles, 16 m-tiles, 2*KSPLIT + 1), block 256.
//  z < 2*KSPLIT : proj — 64x64 tile, 4 waves (2x2), KCHUNK=192 staged once as
//                 bf16, 6 MFMA K-steps (m91 gemm_bt fragment recipe).
//  z == 2*KSPLIT: 64 inv blocks (b = mt*4+nt); block 0 also writes scaled g.
__global__ __launch_bounds__(256) void proj_inv_kernel(const float* __restrict__ za,
                                                       const float* __restrict__ zb,
                                                       const float* __restrict__ slices,
                                                       float* __restrict__ w, int npart) {
    const int tid = threadIdx.x;

    if (blockIdx.z == 2 * KSPLIT) {
        // ---- inv path: 64 blocks * 256 threads * 3 float4 = 256*768 ----
        __shared__ float wred[4];
        const int b = blockIdx.y * 4 + blockIdx.x;      // 0..63
        const float4* A = (const float4*)za;
        const float4* B = (const float4*)zb;
        float p = 0.f;
#pragma unroll
        for (int i = 0; i < 3; ++i) {
            int idx = b * 768 + i * 256 + tid;
            float4 a = A[idx], bb = B[idx];
            float dx = a.x - bb.x, dy = a.y - bb.y, dz = a.z - bb.z, dw = a.w - bb.w;
            p += dx * dx + dy * dy + dz * dz + dw * dw;
        }
        float s = block_sum_256(p, wred, tid);
        if (tid == 0) w[INV_OFF + b] = s;
        if (b == 0 && tid < K_REF) {
            float q = 0.01f + 0.06125f * (float)tid;
            w[G_OFF + tid] = erfinvf(2.0f * q - 1.0f) * 1.41421356237309504880f * SCALE_A;
        }
        return;
    }

    // ---- proj path ----
    __shared__ unsigned short lA[64][LPITCH];
    __shared__ unsigned short lB[64][LPITCH];
    const int nt = blockIdx.x;            // 0..3
    const int mt = blockIdx.y;            // 0..15
    const int zi = blockIdx.z >> 2;       // 0..1
    const int kc = blockIdx.z & 3;        // 0..3
    const float* Z = zi ? zb : za;
    const int m0 = mt * 64, n0 = nt * 64;
    const int kbase = kc * KCHUNK;

    // stage: 64 rows x 192 k, f32 -> bf16 (hw v_cvt_pk_bf16_f32 via intrinsic)
    {
        const int r = tid >> 2;           // 0..63
        const int c4 = tid & 3;           // float4 col group
        const float* Ap = slices + (size_t)(m0 + r) * DIM + kbase + c4 * 4;
        const float* Bp = Z + (size_t)(n0 + r) * DIM + kbase + c4 * 4;
        unsigned short* la = &lA[r][c4 * 4];
        unsigned short* lb = &lB[r][c4 * 4];
#pragma unroll
        for (int i = 0; i < 12; ++i) {
            float4 av = *(const float4*)(Ap + i * 16);
            float4 bv = *(const float4*)(Bp + i * 16);
            uint2 ap, bp;
            ap.x = pkbf(av.x, av.y); ap.y = pkbf(av.z, av.w);
            bp.x = pkbf(bv.x, bv.y); bp.y = pkbf(bv.z, bv.w);
            *(uint2*)(la + i * 16) = ap;
            *(uint2*)(lb + i * 16) = bp;
        }
    }
    __syncthreads();

    // compute: 4 waves, each a 32x32 quadrant (2x2 of 16x16 MFMA tiles)
    const int wv = tid >> 6;
    const int wr = wv >> 1, wc = wv & 1;
    const int lane = tid & 63;
    const int fr = lane & 15, fq = lane >> 4;

    f32x4_t acc00 = {0.f, 0.f, 0.f, 0.f}, acc01 = acc00, acc10 = acc00, acc11 = acc00;
    const int ra0 = wr * 32 + fr, ra1 = ra0 + 16;
    const int rb0 = wc * 32 + fr, rb1 = rb0 + 16;
#pragma unroll
    for (int ks = 0; ks < KCHUNK / 32; ++ks) {
        const int k0 = ks * 32 + fq * 8;
        bf16x8_t a0 = *(const bf16x8_t*)&lA[ra0][k0];
        bf16x8_t a1 = *(const bf16x8_t*)&lA[ra1][k0];
        bf16x8_t b0 = *(const bf16x8_t*)&lB[rb0][k0];
        bf16x8_t b1 = *(const bf16x8_t*)&lB[rb1][k0];
        acc00 = __builtin_amdgcn_mfma_f32_16x16x32_bf16(a0, b0, acc00, 0, 0, 0);
        acc01 = __builtin_amdgcn_mfma_f32_16x16x32_bf16(a0, b1, acc01, 0, 0, 0);
        acc10 = __builtin_amdgcn_mfma_f32_16x16x32_bf16(a1, b0, acc10, 0, 0, 0);
        acc11 = __builtin_amdgcn_mfma_f32_16x16x32_bf16(a1, b1, acc11, 0, 0, 0);
    }

    // C-write: row = base_m + fq*4 + j, col = base_n + fr
    const int rowB = m0 + wr * 32 + fq * 4;
    const int colB = n0 + wc * 32 + fr;
    if (npart == KSPLIT) {
        float* X = w + XP_OFF + ((size_t)zi * KSPLIT + kc) * XSZ;
#pragma unroll
        for (int j = 0; j < 4; ++j) {
            X[(size_t)(rowB + j) * NPTS + colB]           = acc00[j];
            X[(size_t)(rowB + j) * NPTS + colB + 16]      = acc01[j];
            X[(size_t)(rowB + 16 + j) * NPTS + colB]      = acc10[j];
            X[(size_t)(rowB + 16 + j) * NPTS + colB + 16] = acc11[j];
        }
    } else {
        float* X = w + XP_OFF + (size_t)zi * XSZ;
#pragma unroll
        for (int j = 0; j < 4; ++j) {
            atomicAdd(X + (size_t)(rowB + j) * NPTS + colB,           acc00[j]);
            atomicAdd(X + (size_t)(rowB + j) * NPTS + colB + 16,      acc01[j]);
            atomicAdd(X + (size_t)(rowB + 16 + j) * NPTS + colB,      acc10[j]);
            atomicAdd(X + (size_t)(rowB + 16 + j) * NPTS + colB + 16, acc11[j]);
        }
    }
}

// ---------------- per-slice sigreg (t1 + t2), factored-exp form -------------
// exp2(-(yv-yj)^2) = exp2(-yv^2) * exp2(fma(2yv, yj, -yj^2)); LDS holds
// (yj, -yj^2) float2 pairs -> inner loop is 1 fma + 1 exp + 1 add per key.
// t1 off-diag via circular offsets o=1..128: total = 2*sum - S_128 (+ diag N).
// grid: (NSLICES, 2); block 256 (one thread per sample point).
template <int NPART>
__global__ __launch_bounds__(256) void sigreg_kernel(float* __restrict__ w) {
    __shared__ float2 ys2[2 * NPTS];   // duplicated (y, -y^2): base + imm offset reads
    __shared__ float2 gsh2[K_REF];
    __shared__ float wredA[4], wredB[4];
    const int m = blockIdx.x;
    const int zi = blockIdx.y;
    const int tid = threadIdx.x;

    const float* Xb = w + XP_OFF + (size_t)zi * NPART * XSZ + (size_t)m * NPTS + tid;
    float xp[NPART];
#pragma unroll
    for (int p = 0; p < NPART; ++p) xp[p] = Xb[(size_t)p * XSZ];   // loads in flight
    if (tid < K_REF) {
        float gv = w[G_OFF + tid];
        gsh2[tid] = make_float2(gv, -gv * gv);
    }
    float xv = 0.f;
#pragma unroll
    for (int p = 0; p < NPART; ++p) xv += xp[p];

    // one reduction round for both sum(x) and sum(x^2)
    float r1 = wave_sum(xv);
    float r2 = wave_sum(xv * xv);
    if ((tid & 63) == 0) { wredA[tid >> 6] = r1; wredB[tid >> 6] = r2; }
    __syncthreads();
    float sumx  = (wredA[0] + wredA[1]) + (wredA[2] + wredA[3]);
    float sumx2 = (wredB[0] + wredB[1]) + (wredB[2] + wredB[3]);
    float mu = sumx * (1.0f / NPTS);
    float ss = sumx2 - mu * sumx;                  // = sum((x-mu)^2), mu^2 << var here
    float sd = sqrtf(ss * (1.0f / (NPTS - 1))) + 1e-6f;
    float yv = (xv - mu) / sd * SCALE_A;
    float2 pr = make_float2(yv, -yv * yv);
    ys2[tid] = pr;
    ys2[tid + NPTS] = pr;
    __syncthreads();

    const float av = 2.0f * yv;
    const float fac = EXP2(-yv * yv);
    float a0 = 0.f, a1 = 0.f, a2 = 0.f, a3 = 0.f;
#pragma unroll
    for (int t = 0; t < 32; ++t) {                 // o = 4t+1 .. 4t+4 (covers 1..128)
        float2 k1 = ys2[tid + 4 * t + 1];
        float2 k2 = ys2[tid + 4 * t + 2];
        float2 k3 = ys2[tid + 4 * t + 3];
        float2 k4 = ys2[tid + 4 * t + 4];
        a0 += EXP2(fmaf(av, k1.x, k1.y));
        a1 += EXP2(fmaf(av, k2.x, k2.y));
        a2 += EXP2(fmaf(av, k3.x, k3.y));
        a3 += EXP2(fmaf(av, k4.x, k4.y));
    }
    float2 kl = ys2[tid + 128];
    float s128 = fac * EXP2(fmaf(av, kl.x, kl.y));
    float s1 = ((a0 + a1) + (a2 + a3)) * fac;      // sum over o=1..128
    float sg = 0.f;
#pragma unroll
    for (int k = 0; k < K_REF; ++k) {
        float2 g = gsh2[k];
        sg += EXP2(fmaf(av, g.x, g.y));
    }
    sg *= fac;
    // off-diag = 2*sum(o=1..128) - S_128 ; diagonal N added at tid 0
    float c = (2.0f * s1 - s128) * INV_N2 - sg * T2_SC;
    if (tid == 0) c += (float)NPTS * INV_N2;
    float v = wave_sum(c);
    if ((tid & 63) == 0) wredA[tid >> 6] = v;      // safe: all reads were pre-barrier
    __syncthreads();
    if (tid == 0) {
        float tot = (wredA[0] + wredA[1]) + (wredA[2] + wredA[3]);
        w[SIG_OFF + zi * NSLICES + m] = tot * (0.5f / (float)NSLICES);
    }
}

// ---------------- final: reduce slots + t3 + combine ------------------------
__global__ __launch_bounds__(256) void final_kernel(const float* __restrict__ w,
                                                    float* __restrict__ out) {
    __shared__ float wred[4];
    __shared__ float gsh[K_REF];
    const int tid = threadIdx.x;
    if (tid < K_REF) gsh[tid] = w[G_OFF + tid];
    float sv = 0.f;
#pragma unroll
    for (int i = 0; i < 8; ++i) sv += w[SIG_OFF + i * 256 + tid];
    float iv = (tid < 64) ? w[INV_OFF + tid] : 0.f;
    float sig = block_sum_256(sv, wred, tid);
    float inv = block_sum_256(iv, wred, tid);
    // t3 over 289 pairs, parallel (gsh already scaled by SCALE_A)
    float t3p = 0.f;
    for (int idx = tid; idx < K_REF * K_REF; idx += 256) {
        int k = idx / K_REF, l = idx - k * K_REF;
        float d = gsh[k] - gsh[l];
        t3p += EXP2(-(d * d));
    }
    float t3 = block_sum_256(t3p, wred, tid) * (1.0f / ((float)K_REF * (float)K_REF));
    if (tid == 0) {
        out[0] = 25.0f * inv * (1.0f / ((float)NPTS * (float)DIM))
               + 25.0f * (sig + t3);
    }
}

extern "C" void kernel_launch(void* const* d_in, const int* in_sizes, int n_in,
                              void* d_out, int out_size, void* d_ws, size_t ws_size,
                              hipStream_t stream) {
    const float* za = (const float*)d_in[0];
    const float* zb = (const float*)d_in[1];
    const float* slices = (const float*)d_in[2];
    float* out = (float*)d_out;
    float* w = (float*)d_ws;

    const size_t need_full = (size_t)(XP_OFF + 2 * KSPLIT * XSZ) * sizeof(float); // ~8.4 MB
    const int npart = (ws_size >= need_full) ? KSPLIT : 1;

    if (npart == 1)   // fallback only (harness ws is plenty; never taken)
        hipMemsetAsync(w + XP_OFF, 0, (size_t)2 * XSZ * sizeof(float), stream);

    dim3 pg(4, 16, 2 * KSPLIT + 1);
    proj_inv_kernel<<<pg, 256, 0, stream>>>(za, zb, slices, w, npart);
    dim3 sg(NSLICES, 2);
    if (npart == KSPLIT)
        sigreg_kernel<KSPLIT><<<sg, 256, 0, stream>>>(w);
    else
        sigreg_kernel<1><<<sg, 256, 0, stream>>>(w);
    final_kernel<<<1, 256, 0, stream>>>(w, out);
}